// Round 1
// baseline (199.097 us; speedup 1.0000x reference)
//
#include <hip/hip_runtime.h>
#include <hip/hip_bf16.h>

// HypoNerf fused MLP on MI355X (gfx950).
// B=16, N=16384, H=256, PE: 60 freqs -> sin/cos -> 120 (padded to 128).
// Strategy: prep kernel converts weights to bf16 W^T in d_ws; main kernel
// fuses PE + 5 Linear/ReLU layers + final projection, activations resident
// in LDS, weights streamed from L2 as MFMA B-fragments (no K-loop barriers).

#define H 256
#define MT 128          // rows per block
#define HP 264          // padded h row stride (264*2B = 528B = 33*16B: b128 conflict-free, 16B aligned)
#define PE_NF 60

typedef __attribute__((ext_vector_type(8))) short s16x8;   // 8 bf16 (4 VGPRs)
typedef __attribute__((ext_vector_type(4))) float f32x4;   // MFMA accumulator

static __device__ __forceinline__ unsigned short f2bf(float v) {
  // round-to-nearest-even fp32 -> bf16
  unsigned int u = __float_as_uint(v);
  return (unsigned short)((u + 0x7FFFu + ((u >> 16) & 1u)) >> 16);
}
static __device__ __forceinline__ float bf2f(unsigned short u) {
  return __uint_as_float(((unsigned int)u) << 16);
}

// ---------------------------------------------------------------------------
// Prep: W^T bf16 (k-contiguous rows) + fp32 biases into ws.
//   z = blockIdx.z in [0,80): li = z>>4 (layer 0..4), b = z&15
//   layer 0: Ks=120 -> Kd=128 (zero-padded); layers 1-4: 256 -> 256
// ---------------------------------------------------------------------------
__global__ __launch_bounds__(256) void prep_weights(
    const float* __restrict__ wb0, const float* __restrict__ wb1,
    const float* __restrict__ wb2, const float* __restrict__ wb3,
    const float* __restrict__ wb4,
    unsigned short* __restrict__ w0t, unsigned short* __restrict__ w14t,
    float* __restrict__ biases) {
  int z = blockIdx.z;
  int li = z >> 4, b = z & 15;
  int k0 = blockIdx.x * 32;   // 0..7 (layer0 uses 0..3)
  int n0 = blockIdx.y * 32;   // 0..7
  int Ks, Kd;
  const float* src;
  unsigned short* dst;
  if (li == 0) {
    Ks = 120; Kd = 128;
    if (k0 >= 128) return;              // block-uniform early-out, no barrier hazard
    src = wb0 + (size_t)b * 121 * H;
    dst = w0t + (size_t)b * H * 128;
  } else {
    Ks = 256; Kd = 256;
    const float* srcs[4] = {wb1, wb2, wb3, wb4};
    src = srcs[li - 1] + (size_t)b * 257 * H;
    dst = w14t + ((size_t)(li - 1) * 16 + b) * H * 256;
  }
  __shared__ float tile[32][33];
  int tx = threadIdx.x & 31, ty0 = threadIdx.x >> 5;
#pragma unroll
  for (int i = 0; i < 4; ++i) {
    int k = k0 + ty0 + i * 8;
    tile[ty0 + i * 8][tx] = (k < Ks) ? src[(size_t)k * H + n0 + tx] : 0.f;
  }
  if (k0 == 0 && ty0 == 0)   // bias = last row of wb
    biases[((size_t)li * 16 + b) * H + n0 + tx] = src[(size_t)Ks * H + n0 + tx];
  __syncthreads();
#pragma unroll
  for (int i = 0; i < 4; ++i) {
    int n = n0 + ty0 + i * 8;
    dst[(size_t)n * Kd + k0 + tx] = f2bf(tile[tx][ty0 + i * 8]);
  }
}

// ---------------------------------------------------------------------------
// Main fused kernel. 256 threads = 4 waves; wave w -> cols [64w, 64w+64),
// all 128 rows. acc[8][4] 16x16 tiles (128 VGPRs).
// A-frag: lane holds h[rt*16 + (l&15)][k0 + (l>>4)*8 .. +7]  (ds_read_b128)
// B-frag: lane holds W^T[col][k0 + (l>>4)*8 .. +7]           (global dwordx4, L2-hot)
// C:      col = colbase + (l&15), row = rt*16 + (l>>4)*4 + reg   [m89-verified]
// ---------------------------------------------------------------------------
__global__ __launch_bounds__(256, 2) void hyponerf_main(
    const float* __restrict__ x, const float* __restrict__ rfreq,
    const float* __restrict__ wbout,
    const unsigned short* __restrict__ w0t, const unsigned short* __restrict__ w14t,
    const float* __restrict__ biases, float* __restrict__ out) {
  __shared__ __align__(16) unsigned short h_s[MT * HP];  // 67584 B
  __shared__ float fr_s[PE_NF * 3];                      // 720 B
  __shared__ float x_s[MT * 3];                          // 1536 B
  __shared__ float wout_s[H + 1];                        // 1028 B

  // XCD-aware swizzle: 2048 blocks, 8 XCDs -> each XCD gets 2 contiguous batches
  int bid = blockIdx.x;
  int logical = (bid & 7) * 256 + (bid >> 3);
  int b  = logical >> 7;
  int mt = logical & 127;

  int t = threadIdx.x;
  int w = t >> 6, l = t & 63;
  int rlane = l & 15;          // row (A) / col (B) within 16-tile
  int kgrp  = l >> 4;          // 0..3
  int klane = kgrp * 8;
  int colb  = w * 64 + rlane;  // this lane's output column base

  // stage x, scaled freqs, w_out
  const float* xg = x + ((size_t)b * 16384 + (size_t)mt * MT) * 3;
  for (int i = t; i < MT * 3; i += 256) x_s[i] = xg[i];
  for (int i = t; i < PE_NF * 3; i += 256) fr_s[i] = rfreq[i] * 20.0f;  // * (PE_DIM//2)
  for (int i = t; i < H + 1; i += 256) wout_s[i] = wbout[(size_t)b * (H + 1) + i];
  __syncthreads();

  // ---- Gaussian PE: h[r][f] = sin(k), h[r][60+f] = cos(k); pad 120..127 = 0
  {
    int r = t >> 1;
    int fb = (t & 1) * 30;
    float x0 = x_s[r * 3 + 0], x1 = x_s[r * 3 + 1], x2 = x_s[r * 3 + 2];
#pragma unroll
    for (int j = 0; j < 30; ++j) {
      int f = fb + j;
      float kv = x0 * fr_s[f * 3 + 0] + x1 * fr_s[f * 3 + 1] + x2 * fr_s[f * 3 + 2];
      float sv, cv;
      __sincosf(kv, &sv, &cv);
      h_s[r * HP + f]      = f2bf(sv);
      h_s[r * HP + 60 + f] = f2bf(cv);
    }
    if ((t & 1) == 0) {
#pragma unroll
      for (int p = 120; p < 128; ++p) h_s[r * HP + p] = 0;
    }
  }
  __syncthreads();

  // ---- 5 fused Linear+ReLU layers
#pragma unroll 1
  for (int li = 0; li < 5; ++li) {
    const int K = (li == 0) ? 128 : 256;
    const unsigned short* wl = (li == 0)
        ? (w0t + (size_t)b * H * 128)
        : (w14t + ((size_t)(li - 1) * 16 + b) * H * 256);
    const float* bl = biases + ((size_t)li * 16 + b) * H;

    f32x4 acc[8][4];
#pragma unroll
    for (int rt = 0; rt < 8; ++rt)
#pragma unroll
      for (int ct = 0; ct < 4; ++ct)
        acc[rt][ct] = (f32x4){0.f, 0.f, 0.f, 0.f};

    int aoff[8];
#pragma unroll
    for (int rt = 0; rt < 8; ++rt) aoff[rt] = (rt * 16 + rlane) * HP + klane;
    const unsigned short* wp[4];
#pragma unroll
    for (int ct = 0; ct < 4; ++ct)
      wp[ct] = wl + (size_t)(colb + ct * 16) * K + klane;

    const int nkt = K >> 5;
#pragma unroll 1
    for (int kt = 0; kt < nkt; ++kt) {
      s16x8 bfr[4], afr[8];
#pragma unroll
      for (int ct = 0; ct < 4; ++ct) {
        bfr[ct] = *(const s16x8*)wp[ct];
        wp[ct] += 32;
      }
#pragma unroll
      for (int rt = 0; rt < 8; ++rt)
        afr[rt] = *(const s16x8*)&h_s[aoff[rt] + kt * 32];
#pragma unroll
      for (int rt = 0; rt < 8; ++rt)
#pragma unroll
        for (int ct = 0; ct < 4; ++ct)
          acc[rt][ct] = __builtin_amdgcn_mfma_f32_16x16x32_bf16(
              afr[rt], bfr[ct], acc[rt][ct], 0, 0, 0);
    }
    __syncthreads();   // all h reads done before overwrite

    // epilogue: bias + ReLU + bf16 -> h_s
    float bc[4];
#pragma unroll
    for (int ct = 0; ct < 4; ++ct) bc[ct] = bl[colb + ct * 16];
#pragma unroll
    for (int rt = 0; rt < 8; ++rt)
#pragma unroll
      for (int ct = 0; ct < 4; ++ct)
#pragma unroll
        for (int g = 0; g < 4; ++g) {
          float v = acc[rt][ct][g] + bc[ct];
          v = fmaxf(v, 0.f);
          h_s[(rt * 16 + kgrp * 4 + g) * HP + colb + ct * 16] = f2bf(v);
        }
    __syncthreads();   // h ready for next layer / final
  }

  // ---- final projection: out[r] = h[r][:] . wout + bias_out
  {
    int r = t >> 1;
    int kb = (t & 1) * 128;
    float sum = 0.f;
#pragma unroll
    for (int c = 0; c < 16; ++c) {
      int kc = kb + ((c + r) & 15) * 8;   // rotate chunks -> spread LDS banks
      const s16x8 hv = *(const s16x8*)&h_s[r * HP + kc];
#pragma unroll
      for (int j = 0; j < 8; ++j)
        sum += bf2f((unsigned short)hv[j]) * wout_s[kc + j];
    }
    sum += __shfl_xor(sum, 1);
    if ((t & 1) == 0)
      out[(size_t)b * 16384 + (size_t)mt * MT + r] = sum + wout_s[H];
  }
}

// ---------------------------------------------------------------------------
extern "C" void kernel_launch(void* const* d_in, const int* in_sizes, int n_in,
                              void* d_out, int out_size, void* d_ws, size_t ws_size,
                              hipStream_t stream) {
  const float* x     = (const float*)d_in[0];
  const float* wb0   = (const float*)d_in[1];
  const float* wb1   = (const float*)d_in[2];
  const float* wb2   = (const float*)d_in[3];
  const float* wb3   = (const float*)d_in[4];
  const float* wb4   = (const float*)d_in[5];
  const float* wbout = (const float*)d_in[6];
  const float* rfreq = (const float*)d_in[7];
  float* out = (float*)d_out;

  char* ws = (char*)d_ws;
  unsigned short* w0t  = (unsigned short*)ws;                               // [16][256][128] bf16
  unsigned short* w14t = (unsigned short*)(ws + (size_t)16 * 256 * 128 * 2); // [4][16][256][256] bf16
  float* biases = (float*)(ws + (size_t)16 * 256 * 128 * 2
                              + (size_t)4 * 16 * 256 * 256 * 2);             // [5][16][256] f32

  prep_weights<<<dim3(8, 8, 80), 256, 0, stream>>>(wb0, wb1, wb2, wb3, wb4,
                                                   w0t, w14t, biases);
  hyponerf_main<<<dim3(2048), 256, 0, stream>>>(x, rfreq, wbout, w0t, w14t,
                                                biases, out);
}

// Round 2
// 193.829 us; speedup vs baseline: 1.0272x; 1.0272x over previous
//
#include <hip/hip_runtime.h>
#include <hip/hip_bf16.h>

// HypoNerf fused MLP on MI355X (gfx950). R2:
//  - swapped-operand MFMA (C = W^T·h^T): lane holds 4 consecutive out-cols
//    of one row -> packed b64 epilogue stores, bias folded into acc init
//  - XOR-swizzled h LDS layout [128][256] (chunk16 ^ row&7): balanced banks
//  - register ping-pong B-fragment prefetch (hides L2 latency in K-loop)

#define H 256
#define MT 128
#define PE_NF 60

typedef __attribute__((ext_vector_type(8))) short s16x8;   // 8 bf16
typedef __attribute__((ext_vector_type(4))) float f32x4;   // MFMA acc

static __device__ __forceinline__ unsigned short f2bf(float v) {
  unsigned int u = __float_as_uint(v);
  return (unsigned short)((u + 0x7FFFu + ((u >> 16) & 1u)) >> 16);
}
static __device__ __forceinline__ float bf2f(unsigned short u) {
  return __uint_as_float(((unsigned int)u) << 16);
}
// swizzled 16B-chunk index within a 256-elem (32-chunk) row
static __device__ __forceinline__ int hswz(int row, int chunk) {
  return (chunk & ~7) | ((chunk ^ row) & 7);
}

// ---------------------------------------------------------------------------
// Prep: W^T bf16 (k-contiguous rows) + fp32 biases into ws. (unchanged)
// ---------------------------------------------------------------------------
__global__ __launch_bounds__(256) void prep_weights(
    const float* __restrict__ wb0, const float* __restrict__ wb1,
    const float* __restrict__ wb2, const float* __restrict__ wb3,
    const float* __restrict__ wb4,
    unsigned short* __restrict__ w0t, unsigned short* __restrict__ w14t,
    float* __restrict__ biases) {
  int z = blockIdx.z;
  int li = z >> 4, b = z & 15;
  int k0 = blockIdx.x * 32;
  int n0 = blockIdx.y * 32;
  int Ks, Kd;
  const float* src;
  unsigned short* dst;
  if (li == 0) {
    Ks = 120; Kd = 128;
    if (k0 >= 128) return;
    src = wb0 + (size_t)b * 121 * H;
    dst = w0t + (size_t)b * H * 128;
  } else {
    Ks = 256; Kd = 256;
    const float* srcs[4] = {wb1, wb2, wb3, wb4};
    src = srcs[li - 1] + (size_t)b * 257 * H;
    dst = w14t + ((size_t)(li - 1) * 16 + b) * H * 256;
  }
  __shared__ float tile[32][33];
  int tx = threadIdx.x & 31, ty0 = threadIdx.x >> 5;
#pragma unroll
  for (int i = 0; i < 4; ++i) {
    int k = k0 + ty0 + i * 8;
    tile[ty0 + i * 8][tx] = (k < Ks) ? src[(size_t)k * H + n0 + tx] : 0.f;
  }
  if (k0 == 0 && ty0 == 0)
    biases[((size_t)li * 16 + b) * H + n0 + tx] = src[(size_t)Ks * H + n0 + tx];
  __syncthreads();
#pragma unroll
  for (int i = 0; i < 4; ++i) {
    int n = n0 + ty0 + i * 8;
    dst[(size_t)n * Kd + k0 + tx] = f2bf(tile[tx][ty0 + i * 8]);
  }
}

// ---------------------------------------------------------------------------
// One fused Linear+ReLU layer.
// w_frag (A): lane holds W^T[n = w*64+ct*16+rlane][kgrp*8 + kt*32 .. +7]
// h_frag (B): lane holds h[m = rt*16+rlane][kgrp*8 + kt*32 .. +7] (swizzled)
// C (swapped): m = tile_m + (lane&15), n = tile_n + (lane>>4)*4 + reg
// ---------------------------------------------------------------------------
template <int NKT>
static __device__ __forceinline__ void mlp_layer(
    const unsigned short* __restrict__ wl, const float* __restrict__ bl,
    unsigned short* __restrict__ h_s, const int rlane, const int kgrp,
    const int w) {
  const int n_base = w * 64;

  // acc init = bias (per-lane: bias[n_base + ct*16 + kgrp*4 + 0..3])
  f32x4 acc[8][4];
  {
    f32x4 bini[4];
#pragma unroll
    for (int ct = 0; ct < 4; ++ct)
      bini[ct] = *(const f32x4*)(bl + n_base + ct * 16 + kgrp * 4);
#pragma unroll
    for (int rt = 0; rt < 8; ++rt)
#pragma unroll
      for (int ct = 0; ct < 4; ++ct) acc[rt][ct] = bini[ct];
  }

  const unsigned short* wp[4];
#pragma unroll
  for (int ct = 0; ct < 4; ++ct)
    wp[ct] = wl + (size_t)(n_base + ct * 16 + rlane) * (NKT * 32) + kgrp * 8;
  int aoff[8];
#pragma unroll
  for (int rt = 0; rt < 8; ++rt) aoff[rt] = (rt * 16 + rlane) * 256;

  s16x8 bb[2][4];
#pragma unroll
  for (int ct = 0; ct < 4; ++ct) bb[0][ct] = *(const s16x8*)(wp[ct]);

#pragma unroll
  for (int kt = 0; kt < NKT; ++kt) {
    if (kt + 1 < NKT) {
#pragma unroll
      for (int ct = 0; ct < 4; ++ct)
        bb[(kt + 1) & 1][ct] = *(const s16x8*)(wp[ct] + (kt + 1) * 32);
    }
    s16x8 afr[8];
    const int cs = hswz(rlane, kt * 4 + kgrp) * 8;
#pragma unroll
    for (int rt = 0; rt < 8; ++rt)
      afr[rt] = *(const s16x8*)&h_s[aoff[rt] + cs];
#pragma unroll
    for (int rt = 0; rt < 8; ++rt)
#pragma unroll
      for (int ct = 0; ct < 4; ++ct)
        acc[rt][ct] = __builtin_amdgcn_mfma_f32_16x16x32_bf16(
            bb[kt & 1][ct], afr[rt], acc[rt][ct], 0, 0, 0);
  }
  __syncthreads();  // all h reads done before overwrite

  // epilogue: ReLU + pack 4 bf16 -> b64 store  (h[m][n0..n0+3])
  const int sub = (kgrp & 1) * 4;
  const int cbase = w * 8 + (kgrp >> 1);
#pragma unroll
  for (int rt = 0; rt < 8; ++rt) {
    const int m = rt * 16 + rlane;
    const int rowb = m * 256;
#pragma unroll
    for (int ct = 0; ct < 4; ++ct) {
      const int cs = hswz(m, cbase + ct * 2);
      float v0 = fmaxf(acc[rt][ct][0], 0.f);
      float v1 = fmaxf(acc[rt][ct][1], 0.f);
      float v2 = fmaxf(acc[rt][ct][2], 0.f);
      float v3 = fmaxf(acc[rt][ct][3], 0.f);
      union { __hip_bfloat162 h2[2]; uint2 u; } pk;
      pk.h2[0] = __float22bfloat162_rn(float2{v0, v1});
      pk.h2[1] = __float22bfloat162_rn(float2{v2, v3});
      *(uint2*)&h_s[rowb + cs * 8 + sub] = pk.u;
    }
  }
  __syncthreads();  // h ready for next layer / final
}

// ---------------------------------------------------------------------------
__global__ __launch_bounds__(256, 2) void hyponerf_main(
    const float* __restrict__ x, const float* __restrict__ rfreq,
    const float* __restrict__ wbout,
    const unsigned short* __restrict__ w0t, const unsigned short* __restrict__ w14t,
    const float* __restrict__ biases, float* __restrict__ out) {
  __shared__ __align__(16) unsigned short h_s[MT * 256];  // 65536 B
  __shared__ float fr_s[PE_NF * 3];
  __shared__ float x_s[MT * 3];
  __shared__ float wout_s[H + 1];

  // XCD-aware swizzle: 2048 blocks, 8 XCDs -> contiguous batches per XCD
  int bid = blockIdx.x;
  int logical = (bid & 7) * 256 + (bid >> 3);
  int b  = logical >> 7;
  int mt = logical & 127;

  int t = threadIdx.x;
  int w = t >> 6, l = t & 63;
  int rlane = l & 15;
  int kgrp  = l >> 4;

  const float* xg = x + ((size_t)b * 16384 + (size_t)mt * MT) * 3;
  for (int i = t; i < MT * 3; i += 256) x_s[i] = xg[i];
  for (int i = t; i < PE_NF * 3; i += 256) fr_s[i] = rfreq[i] * 20.0f;
  for (int i = t; i < H + 1; i += 256) wout_s[i] = wbout[(size_t)b * (H + 1) + i];
  __syncthreads();

  // ---- Gaussian PE (swizzled writes): h[r][f]=sin, h[r][60+f]=cos, pad->0
  {
    int r = t >> 1;
    int fb = (t & 1) * 30;
    float x0 = x_s[r * 3 + 0], x1 = x_s[r * 3 + 1], x2 = x_s[r * 3 + 2];
    int rowb = r * 256;
#pragma unroll
    for (int j = 0; j < 30; ++j) {
      int f = fb + j;
      float kv = x0 * fr_s[f * 3 + 0] + x1 * fr_s[f * 3 + 1] + x2 * fr_s[f * 3 + 2];
      float sv, cv;
      __sincosf(kv, &sv, &cv);
      h_s[rowb + hswz(r, f >> 3) * 8 + (f & 7)] = f2bf(sv);
      int g = 60 + f;
      h_s[rowb + hswz(r, g >> 3) * 8 + (g & 7)] = f2bf(cv);
    }
    if ((t & 1) == 0) {
      int cs = hswz(r, 15) * 8;
#pragma unroll
      for (int p = 0; p < 8; ++p) h_s[rowb + cs + p] = 0;
    }
  }
  __syncthreads();

  // ---- 5 fused Linear+ReLU layers
  mlp_layer<4>(w0t + (size_t)b * H * 128, biases + (size_t)b * H, h_s,
               rlane, kgrp, w);
#pragma unroll 1
  for (int li = 1; li < 5; ++li) {
    mlp_layer<8>(w14t + ((size_t)(li - 1) * 16 + b) * H * 256,
                 biases + ((size_t)li * 16 + b) * H, h_s, rlane, kgrp, w);
  }

  // ---- final projection: out[r] = h[r][:] . wout + bias_out
  {
    int r = t >> 1;
    int cb = (t & 1) * 16;
    int rowb = r * 256;
    float sum = 0.f;
#pragma unroll
    for (int c = 0; c < 16; ++c) {
      int ch = cb + c;
      const s16x8 hv = *(const s16x8*)&h_s[rowb + hswz(r, ch) * 8];
#pragma unroll
      for (int j = 0; j < 8; ++j)
        sum += bf2f((unsigned short)hv[j]) * wout_s[ch * 8 + j];
    }
    sum += __shfl_xor(sum, 1);
    if ((t & 1) == 0)
      out[(size_t)b * 16384 + (size_t)mt * MT + r] = sum + wout_s[H];
  }
}

// ---------------------------------------------------------------------------
extern "C" void kernel_launch(void* const* d_in, const int* in_sizes, int n_in,
                              void* d_out, int out_size, void* d_ws, size_t ws_size,
                              hipStream_t stream) {
  const float* x     = (const float*)d_in[0];
  const float* wb0   = (const float*)d_in[1];
  const float* wb1   = (const float*)d_in[2];
  const float* wb2   = (const float*)d_in[3];
  const float* wb3   = (const float*)d_in[4];
  const float* wb4   = (const float*)d_in[5];
  const float* wbout = (const float*)d_in[6];
  const float* rfreq = (const float*)d_in[7];
  float* out = (float*)d_out;

  char* ws = (char*)d_ws;
  unsigned short* w0t  = (unsigned short*)ws;                                // [16][256][128]
  unsigned short* w14t = (unsigned short*)(ws + (size_t)16 * 256 * 128 * 2); // [4][16][256][256]
  float* biases = (float*)(ws + (size_t)16 * 256 * 128 * 2
                              + (size_t)4 * 16 * 256 * 256 * 2);             // [5][16][256]

  prep_weights<<<dim3(8, 8, 80), 256, 0, stream>>>(wb0, wb1, wb2, wb3, wb4,
                                                   w0t, w14t, biases);
  hyponerf_main<<<dim3(2048), 256, 0, stream>>>(x, rfreq, wbout, w0t, w14t,
                                                biases, out);
}